// Round 3
// baseline (370.855 us; speedup 1.0000x reference)
//
#include <hip/hip_runtime.h>
#include <stdint.h>

#define NN 96
#define DD 64
#define CC 30

typedef float v4f __attribute__((ext_vector_type(4)));

// ws layout (bytes):
//   mat    : float [96*96]        @ 0      (36864 B)
//   eps    : float                @ 36864
//   samesW : uint64 [96][2]       @ 36928  (1536 B)   sames (diag zeroed)
//   srawW  : uint64 [96][2]       @ 38464  (1536 B)   sames_raw
//   cbits  : uint64 [96*96][2]    @ 40000  (147456 B) c[i,p,:] bit rows

__global__ __launch_bounds__(256) void k_prep(
    const float* __restrict__ logits, const float* __restrict__ labels,
    float* __restrict__ mat, float* __restrict__ epsOut,
    uint64_t* __restrict__ samesW, uint64_t* __restrict__ srawW)
{
    __shared__ float xt[DD][NN];          // transposed normalized logits
    __shared__ uint32_t lab[NN];
    __shared__ uint64_t sS[NN][2], rS[NN][2];
    __shared__ float t1s[NN], t2s[NN], qs[NN];
    const int tid = threadIdx.x;

    // label bitmasks
    if (tid < NN) {
        uint32_t b = 0;
        for (int c = 0; c < CC; ++c)
            b |= (labels[tid*CC + c] != 0.0f) ? (1u << c) : 0u;
        lab[tid] = b;
    }
    __syncthreads();

    // sames / sames_raw bit rows; row norms; normalized x (transposed in LDS)
    if (tid < NN) {
        const uint32_t bi = lab[tid];
        uint64_t r0 = 0, r1 = 0;
        for (int j = 0; j < 64; ++j)  r0 |= (uint64_t)((bi & lab[j]) ? 1u : 0u) << j;
        for (int j = 64; j < NN; ++j) r1 |= (uint64_t)((bi & lab[j]) ? 1u : 0u) << (j - 64);
        uint64_t s0 = r0, s1 = r1;
        if (tid < 64) s0 &= ~(1ull << tid); else s1 &= ~(1ull << (tid - 64));
        sS[tid][0] = s0; sS[tid][1] = s1; rS[tid][0] = r0; rS[tid][1] = r1;
        samesW[tid*2] = s0; samesW[tid*2+1] = s1;
        srawW[tid*2]  = r0; srawW[tid*2+1]  = r1;

        float ss = 0.f;
        for (int d = 0; d < DD; ++d) { float v = logits[tid*DD + d]; ss = fmaf(v, v, ss); }
        const float nrm = sqrtf(ss);
        for (int d = 0; d < DD; ++d) xt[d][tid] = logits[tid*DD + d] / nrm;
    }
    __syncthreads();

    // mat = -(x x^T): 6x6 register tile per thread (16x16 thread grid)
    {
        const int ti = tid >> 4, tj = tid & 15;
        const int r0 = ti * 6, c0 = tj * 6;
        float acc[6][6];
        #pragma unroll
        for (int a = 0; a < 6; ++a)
            #pragma unroll
            for (int b = 0; b < 6; ++b) acc[a][b] = 0.f;
        for (int d = 0; d < DD; ++d) {
            float ra[6], rb[6];
            #pragma unroll
            for (int a = 0; a < 6; ++a) ra[a] = xt[d][r0 + a];
            #pragma unroll
            for (int b = 0; b < 6; ++b) rb[b] = xt[d][c0 + b];
            #pragma unroll
            for (int a = 0; a < 6; ++a)
                #pragma unroll
                for (int b = 0; b < 6; ++b) acc[a][b] = fmaf(ra[a], rb[b], acc[a][b]);
        }
        #pragma unroll
        for (int a = 0; a < 6; ++a)
            #pragma unroll
            for (int b = 0; b < 6; ++b)
                mat[(r0 + a)*NN + (c0 + b)] = -acc[a][b];
    }
    __syncthreads();   // global writes within a block are visible after barrier

    // per-row stats -> epsilon
    if (tid < NN) {
        const int i = tid;
        const uint64_t s0 = sS[i][0], s1 = sS[i][1], r0 = rS[i][0], r1 = rS[i][1];
        const int S = __popcll(s0) + __popcll(s1);
        const float P = 0.5f * (float)S * (float)(S - 1);   // = w1.sum(1) = w2.sum(1)
        int pref = 0, dcnt = 0;
        float msum1 = 0.f, msum2 = 0.f, mdsum = 0.f;
        for (int j = 0; j < NN; ++j) {
            const float mv = mat[i*NN + j];
            const bool sb = (j < 64) ? ((s0 >> j) & 1ull) : ((s1 >> (j - 64)) & 1ull);
            const bool db = !((j < 64) ? ((r0 >> j) & 1ull) : ((r1 >> (j - 64)) & 1ull));
            if (sb) {
                msum2 = fmaf(mv, (float)pref, msum2);   // cnt_j = #sames strictly before j
                ++pref;
                msum1 = fmaf(mv, (float)(S - pref), msum1); // cnt_k = #sames strictly after j
            }
            if (db) { ++dcnt; mdsum += mv; }
        }
        const float ds = (float)dcnt;
        t1s[i] = mdsum * P - msum1 * ds;
        t2s[i] = mdsum * P - msum2 * ds;
        qs[i]  = P * ds;
    }
    __syncthreads();
    if (tid == 0) {
        float sum1 = 0.f, sum2 = 0.f, Q = 0.f;
        for (int i = 0; i < NN; ++i) { sum1 += t1s[i]; sum2 += t2s[i]; Q += qs[i]; }
        const float md = (sum1 + sum2) / fmaxf(2.0f * Q, 1.0f);
        epsOut[0] = fmaxf(md * 0.5f, 0.0f);   // relu(mean_delta / K_DELTA), K_DELTA = 2
    }
}

__global__ __launch_bounds__(128) void k_cbits(
    const float* __restrict__ mat, const float* __restrict__ epsP,
    const uint64_t* __restrict__ samesW, const uint64_t* __restrict__ srawW,
    uint64_t* __restrict__ cbits)
{
    const int i = blockIdx.x;
    const int tid = threadIdx.x;
    __shared__ float row[NN];
    if (tid < NN) row[tid] = mat[i*NN + tid];
    __syncthreads();
    if (tid >= NN) return;
    const int p = tid;
    uint64_t c0 = 0, c1 = 0;
    const uint64_t s0 = samesW[i*2], s1 = samesW[i*2+1];
    const bool sp = (p < 64) ? ((s0 >> p) & 1ull) : ((s1 >> (p - 64)) & 1ull);
    if (sp) {
        const float eps = epsP[0];
        const float mp = row[p];
        const uint64_t d0 = ~srawW[i*2], d1 = ~srawW[i*2+1];
        for (int n = 0; n < NN; ++n) {
            const float m = row[n] - mp;
            const bool db = (n < 64) ? ((d0 >> n) & 1ull) : ((d1 >> (n - 64)) & 1ull);
            if (db && (m > 0.0f) && (m <= eps)) {
                if (n < 64) c0 |= 1ull << n; else c1 |= 1ull << (n - 64);
            }
        }
    }
    cbits[(i*NN + p)*2]     = c0;
    cbits[(i*NN + p)*2 + 1] = c1;
}

// One block per rem = i*96 + j (grid 9216). 256 threads x 9 unrolled iters
// cover the 2304 float4 of the (k, n) plane. Uniform row bits hoisted to
// SGPRs; one dwordx4 load per iter for cbits[i,k]; incremental k/q advance
// (no per-element divide); 32-bit word select; j>=k waves skip bit work.
// Regular (cached) stores: A/B vs round-2 showed nontemporal was the suspect
// regressor — L2 write-back staging is how the 6.3 TB/s fill rate is achieved.
__global__ __launch_bounds__(256) void k_mask(
    const uint64_t* __restrict__ cbits, v4f* __restrict__ out)
{
    const uint32_t rem = blockIdx.x;             // i*96 + j
    const uint32_t i = rem / 96u;
    const uint32_t j = rem - i * 96u;
    // row (i,j) bits — block-uniform -> scalar loads/regs
    const uint64_t wj0 = cbits[rem * 2u];
    const uint64_t wj1 = cbits[rem * 2u + 1u];
    const uint32_t wjx = (uint32_t)wj0;           // n 0..31
    const uint32_t wjy = (uint32_t)(wj0 >> 32);   // n 32..63
    const uint32_t wjz = (uint32_t)wj1;           // n 64..95
    const uint4* __restrict__ cb_i = (const uint4*)(cbits + (size_t)i * 192u); // row (i,k) = 16B
    const uint32_t tid = threadIdx.x;

    uint32_t k = tid / 24u;          // pos = it*256 + tid; k = pos/24, q = pos%24
    uint32_t q = tid - k * 24u;
    v4f* o = out + (size_t)rem * 2304u + tid;

    #pragma unroll
    for (int it = 0; it < 9; ++it) {
        v4f v = (v4f){0.f, 0.f, 0.f, 0.f};
        if (j < k) {
            const uint4 wk = cb_i[k];                 // .x: n0-31, .y: n32-63, .z: n64-95
            const uint32_t sel = q >> 3;              // 0,1,2 : which 32-bit word
            const uint32_t sh  = (q * 4u) & 31u;
            const uint32_t wkw = (sel == 0u) ? wk.x : ((sel == 1u) ? wk.y : wk.z);
            const uint32_t wjw = (sel == 0u) ? wjx  : ((sel == 1u) ? wjy  : wjz);
            const uint32_t bits = ((wkw & wjw) >> sh) & 15u;
            v.x = (float)(bits & 1u);
            v.y = (float)((bits >> 1) & 1u);
            v.z = (float)((bits >> 2) & 1u);
            v.w = (float)(bits >> 3);
        }
        *o = v;
        o += 256;
        // advance pos by 256: 256 = 10*24 + 16
        q += 16u; k += 10u;
        if (q >= 24u) { q -= 24u; k += 1u; }
    }
}

extern "C" void kernel_launch(void* const* d_in, const int* in_sizes, int n_in,
                              void* d_out, int out_size, void* d_ws, size_t ws_size,
                              hipStream_t stream) {
    const float* logits = (const float*)d_in[0];
    const float* labels = (const float*)d_in[1];
    char* ws = (char*)d_ws;
    float*    mat    = (float*)(ws + 0);
    float*    eps    = (float*)(ws + 36864);
    uint64_t* samesW = (uint64_t*)(ws + 36928);
    uint64_t* srawW  = (uint64_t*)(ws + 38464);
    uint64_t* cbits  = (uint64_t*)(ws + 40000);

    hipLaunchKernelGGL(k_prep, dim3(1), dim3(256), 0, stream,
                       logits, labels, mat, eps, samesW, srawW);
    hipLaunchKernelGGL(k_cbits, dim3(NN), dim3(128), 0, stream,
                       mat, eps, samesW, srawW, cbits);
    hipLaunchKernelGGL(k_mask, dim3(NN*NN), dim3(256), 0, stream,
                       cbits, (v4f*)d_out);
}

// Round 4
// 353.184 us; speedup vs baseline: 1.0500x; 1.0500x over previous
//
#include <hip/hip_runtime.h>
#include <stdint.h>

#define NN 96
#define DD 64
#define CC 30

// ws layout (bytes):
//   mat    : float [96*96]        @ 0      (36864 B)
//   eps    : float                @ 36864
//   samesW : uint64 [96][2]       @ 36928  (1536 B)   sames (diag zeroed)
//   srawW  : uint64 [96][2]       @ 38464  (1536 B)   sames_raw
//   cbits  : uint64 [96*96][2]    @ 40000  (147456 B) c[i,p,:] bit rows

__global__ __launch_bounds__(512) void k_prep(
    const float* __restrict__ logits, const float* __restrict__ labels,
    float* __restrict__ mat, float* __restrict__ epsOut,
    uint64_t* __restrict__ samesW, uint64_t* __restrict__ srawW)
{
    __shared__ float xt[DD][NN];          // transposed normalized logits
    __shared__ uint32_t lab[NN];
    __shared__ uint64_t sS[NN][2], rS[NN][2];
    __shared__ float t1s[NN], t2s[NN], qs[NN];
    const int tid = threadIdx.x;

    // label bitmasks
    if (tid < NN) {
        uint32_t b = 0;
        for (int c = 0; c < CC; ++c)
            b |= (labels[tid*CC + c] != 0.0f) ? (1u << c) : 0u;
        lab[tid] = b;
    }
    __syncthreads();

    // sames / sames_raw bit rows; row norms; normalized x (transposed in LDS)
    if (tid < NN) {
        const uint32_t bi = lab[tid];
        uint64_t r0 = 0, r1 = 0;
        for (int j = 0; j < 64; ++j)  r0 |= (uint64_t)((bi & lab[j]) ? 1u : 0u) << j;
        for (int j = 64; j < NN; ++j) r1 |= (uint64_t)((bi & lab[j]) ? 1u : 0u) << (j - 64);
        uint64_t s0 = r0, s1 = r1;
        if (tid < 64) s0 &= ~(1ull << tid); else s1 &= ~(1ull << (tid - 64));
        sS[tid][0] = s0; sS[tid][1] = s1; rS[tid][0] = r0; rS[tid][1] = r1;
        samesW[tid*2] = s0; samesW[tid*2+1] = s1;
        srawW[tid*2]  = r0; srawW[tid*2+1]  = r1;

        float ss = 0.f;
        for (int d = 0; d < DD; ++d) { float v = logits[tid*DD + d]; ss = fmaf(v, v, ss); }
        const float nrm = sqrtf(ss);
        for (int d = 0; d < DD; ++d) xt[d][tid] = logits[tid*DD + d] / nrm;
    }
    __syncthreads();

    // mat = -(x x^T): 6x3 register tile per thread (16x32 thread grid, 512 thr).
    // Per-element accumulation order over d is identical to any partition ->
    // bit-exact mat regardless of tiling.
    {
        const int ti = tid >> 5, tj = tid & 31;
        const int r0 = ti * 6, c0 = tj * 3;
        float acc[6][3];
        #pragma unroll
        for (int a = 0; a < 6; ++a)
            #pragma unroll
            for (int b = 0; b < 3; ++b) acc[a][b] = 0.f;
        for (int d = 0; d < DD; ++d) {
            float ra[6], rb[3];
            #pragma unroll
            for (int a = 0; a < 6; ++a) ra[a] = xt[d][r0 + a];
            #pragma unroll
            for (int b = 0; b < 3; ++b) rb[b] = xt[d][c0 + b];
            #pragma unroll
            for (int a = 0; a < 6; ++a)
                #pragma unroll
                for (int b = 0; b < 3; ++b) acc[a][b] = fmaf(ra[a], rb[b], acc[a][b]);
        }
        #pragma unroll
        for (int a = 0; a < 6; ++a)
            #pragma unroll
            for (int b = 0; b < 3; ++b)
                mat[(r0 + a)*NN + (c0 + b)] = -acc[a][b];
    }
    __syncthreads();   // global writes within a block are visible after barrier

    // per-row stats -> epsilon (serial per row: keep exact fp order)
    if (tid < NN) {
        const int i = tid;
        const uint64_t s0 = sS[i][0], s1 = sS[i][1], r0 = rS[i][0], r1 = rS[i][1];
        const int S = __popcll(s0) + __popcll(s1);
        const float P = 0.5f * (float)S * (float)(S - 1);   // = w1.sum(1) = w2.sum(1)
        int pref = 0, dcnt = 0;
        float msum1 = 0.f, msum2 = 0.f, mdsum = 0.f;
        for (int j = 0; j < NN; ++j) {
            const float mv = mat[i*NN + j];
            const bool sb = (j < 64) ? ((s0 >> j) & 1ull) : ((s1 >> (j - 64)) & 1ull);
            const bool db = !((j < 64) ? ((r0 >> j) & 1ull) : ((r1 >> (j - 64)) & 1ull));
            if (sb) {
                msum2 = fmaf(mv, (float)pref, msum2);   // cnt_j = #sames strictly before j
                ++pref;
                msum1 = fmaf(mv, (float)(S - pref), msum1); // cnt_k = #sames strictly after j
            }
            if (db) { ++dcnt; mdsum += mv; }
        }
        const float ds = (float)dcnt;
        t1s[i] = mdsum * P - msum1 * ds;
        t2s[i] = mdsum * P - msum2 * ds;
        qs[i]  = P * ds;
    }
    __syncthreads();
    if (tid == 0) {
        float sum1 = 0.f, sum2 = 0.f, Q = 0.f;
        for (int i = 0; i < NN; ++i) { sum1 += t1s[i]; sum2 += t2s[i]; Q += qs[i]; }
        const float md = (sum1 + sum2) / fmaxf(2.0f * Q, 1.0f);
        epsOut[0] = fmaxf(md * 0.5f, 0.0f);   // relu(mean_delta / K_DELTA), K_DELTA = 2
    }
}

__global__ __launch_bounds__(128) void k_cbits(
    const float* __restrict__ mat, const float* __restrict__ epsP,
    const uint64_t* __restrict__ samesW, const uint64_t* __restrict__ srawW,
    uint64_t* __restrict__ cbits)
{
    const int i = blockIdx.x;
    const int tid = threadIdx.x;
    __shared__ float row[NN];
    if (tid < NN) row[tid] = mat[i*NN + tid];
    __syncthreads();
    if (tid >= NN) return;
    const int p = tid;
    uint64_t c0 = 0, c1 = 0;
    const uint64_t s0 = samesW[i*2], s1 = samesW[i*2+1];
    const bool sp = (p < 64) ? ((s0 >> p) & 1ull) : ((s1 >> (p - 64)) & 1ull);
    if (sp) {
        const float eps = epsP[0];
        const float mp = row[p];
        const uint64_t d0 = ~srawW[i*2], d1 = ~srawW[i*2+1];
        for (int n = 0; n < NN; ++n) {
            const float m = row[n] - mp;
            const bool db = (n < 64) ? ((d0 >> n) & 1ull) : ((d1 >> (n - 64)) & 1ull);
            if (db && (m > 0.0f) && (m <= eps)) {
                if (n < 64) c0 |= 1ull << n; else c1 |= 1ull << (n - 64);
            }
        }
    }
    cbits[(i*NN + p)*2]     = c0;
    cbits[(i*NN + p)*2 + 1] = c1;
}

// grid (9, 9216): blockIdx.y = i*96+j ; 2304 float4 per (i,j) covering (k, n).
// Exact R0 structure — the proven-fastest variant (82,944 tiny blocks, one
// 16-B store per thread). Two restructure attempts (block-per-rem, 9 stores
// per thread, with and without nontemporal) both measured ~+10 us slower.
__global__ __launch_bounds__(256) void k_mask(
    const uint64_t* __restrict__ cbits, float4* __restrict__ out)
{
    const uint32_t rem = blockIdx.y;                       // i*96 + j
    const uint32_t pos = blockIdx.x * 256u + threadIdx.x;  // 0..2303 = k*24 + q
    const uint32_t k = pos / 24u;
    const uint32_t q = pos - k * 24u;
    const uint32_t i = rem / 96u;
    const uint32_t j = rem - i * 96u;
    float4 v = {0.f, 0.f, 0.f, 0.f};
    if (j < k) {
        const uint32_t b = i * 96u + k;
        const uint64_t w0 = cbits[rem*2]   & cbits[b*2];
        const uint64_t w1 = cbits[rem*2+1] & cbits[b*2+1];
        const uint32_t n0 = q * 4u;
        const uint64_t w = (n0 < 64u) ? w0 : w1;
        const uint32_t sh = n0 & 63u;
        v.x = (float)((w >> sh) & 1ull);
        v.y = (float)((w >> (sh + 1)) & 1ull);
        v.z = (float)((w >> (sh + 2)) & 1ull);
        v.w = (float)((w >> (sh + 3)) & 1ull);
    }
    out[(size_t)rem * 2304u + pos] = v;
}

extern "C" void kernel_launch(void* const* d_in, const int* in_sizes, int n_in,
                              void* d_out, int out_size, void* d_ws, size_t ws_size,
                              hipStream_t stream) {
    const float* logits = (const float*)d_in[0];
    const float* labels = (const float*)d_in[1];
    char* ws = (char*)d_ws;
    float*    mat    = (float*)(ws + 0);
    float*    eps    = (float*)(ws + 36864);
    uint64_t* samesW = (uint64_t*)(ws + 36928);
    uint64_t* srawW  = (uint64_t*)(ws + 38464);
    uint64_t* cbits  = (uint64_t*)(ws + 40000);

    hipLaunchKernelGGL(k_prep, dim3(1), dim3(512), 0, stream,
                       logits, labels, mat, eps, samesW, srawW);
    hipLaunchKernelGGL(k_cbits, dim3(NN), dim3(128), 0, stream,
                       mat, eps, samesW, srawW, cbits);
    hipLaunchKernelGGL(k_mask, dim3(9, NN*NN), dim3(256), 0, stream,
                       cbits, (float4*)d_out);
}

// Round 5
// 352.661 us; speedup vs baseline: 1.0516x; 1.0015x over previous
//
#include <hip/hip_runtime.h>
#include <stdint.h>

#define NN 96
#define DD 64
#define CC 30

// ws layout (bytes):
//   mat    : float [96*96]        @ 0      (36864 B)
//   eps    : float                @ 36864
//   samesW : uint64 [96][2]       @ 36928  (1536 B)   sames (diag zeroed)
//   srawW  : uint64 [96][2]       @ 38464  (1536 B)   sames_raw
//   cbits  : uint64 [96*96][2]    @ 40000  (147456 B) c[i,p,:] bit rows

__global__ __launch_bounds__(512) void k_prep(
    const float* __restrict__ logits, const float* __restrict__ labels,
    float* __restrict__ mat, float* __restrict__ epsOut,
    uint64_t* __restrict__ samesW, uint64_t* __restrict__ srawW)
{
    __shared__ float xt[DD][NN];          // transposed normalized logits
    __shared__ float matS[NN][NN];        // LDS copy of mat for the serial stats phase
    __shared__ uint32_t lab[NN];
    __shared__ uint64_t sS[NN][2], rS[NN][2];
    __shared__ float t1s[NN], t2s[NN], qs[NN];
    const int tid = threadIdx.x;

    // label bitmasks
    if (tid < NN) {
        uint32_t b = 0;
        for (int c = 0; c < CC; ++c)
            b |= (labels[tid*CC + c] != 0.0f) ? (1u << c) : 0u;
        lab[tid] = b;
    }
    __syncthreads();

    // sames / sames_raw bit rows; row norms; normalized x (transposed in LDS)
    if (tid < NN) {
        const uint32_t bi = lab[tid];
        uint64_t r0 = 0, r1 = 0;
        for (int j = 0; j < 64; ++j)  r0 |= (uint64_t)((bi & lab[j]) ? 1u : 0u) << j;
        for (int j = 64; j < NN; ++j) r1 |= (uint64_t)((bi & lab[j]) ? 1u : 0u) << (j - 64);
        uint64_t s0 = r0, s1 = r1;
        if (tid < 64) s0 &= ~(1ull << tid); else s1 &= ~(1ull << (tid - 64));
        sS[tid][0] = s0; sS[tid][1] = s1; rS[tid][0] = r0; rS[tid][1] = r1;
        samesW[tid*2] = s0; samesW[tid*2+1] = s1;
        srawW[tid*2]  = r0; srawW[tid*2+1]  = r1;

        float ss = 0.f;
        for (int d = 0; d < DD; ++d) { float v = logits[tid*DD + d]; ss = fmaf(v, v, ss); }
        const float nrm = sqrtf(ss);
        for (int d = 0; d < DD; ++d) xt[d][tid] = logits[tid*DD + d] / nrm;
    }
    __syncthreads();

    // mat = -(x x^T): 6x3 register tile per thread (16x32 thread grid, 512 thr).
    // Per-element accumulation order over d is identical to any partition ->
    // bit-exact mat regardless of tiling. Write both global (for k_cbits) and
    // LDS (for the serial stats phase below — avoids ~200-cycle global loads
    // in a latency-bound single-block phase).
    {
        const int ti = tid >> 5, tj = tid & 31;
        const int r0 = ti * 6, c0 = tj * 3;
        float acc[6][3];
        #pragma unroll
        for (int a = 0; a < 6; ++a)
            #pragma unroll
            for (int b = 0; b < 3; ++b) acc[a][b] = 0.f;
        for (int d = 0; d < DD; ++d) {
            float ra[6], rb[3];
            #pragma unroll
            for (int a = 0; a < 6; ++a) ra[a] = xt[d][r0 + a];
            #pragma unroll
            for (int b = 0; b < 3; ++b) rb[b] = xt[d][c0 + b];
            #pragma unroll
            for (int a = 0; a < 6; ++a)
                #pragma unroll
                for (int b = 0; b < 3; ++b) acc[a][b] = fmaf(ra[a], rb[b], acc[a][b]);
        }
        #pragma unroll
        for (int a = 0; a < 6; ++a)
            #pragma unroll
            for (int b = 0; b < 3; ++b) {
                const float mv = -acc[a][b];
                mat[(r0 + a)*NN + (c0 + b)] = mv;
                matS[r0 + a][c0 + b] = mv;
            }
    }
    __syncthreads();

    // per-row stats -> epsilon (serial per row: keep exact fp order; LDS reads)
    if (tid < NN) {
        const int i = tid;
        const uint64_t s0 = sS[i][0], s1 = sS[i][1], r0 = rS[i][0], r1 = rS[i][1];
        const int S = __popcll(s0) + __popcll(s1);
        const float P = 0.5f * (float)S * (float)(S - 1);   // = w1.sum(1) = w2.sum(1)
        int pref = 0, dcnt = 0;
        float msum1 = 0.f, msum2 = 0.f, mdsum = 0.f;
        for (int j = 0; j < NN; ++j) {
            const float mv = matS[i][j];
            const bool sb = (j < 64) ? ((s0 >> j) & 1ull) : ((s1 >> (j - 64)) & 1ull);
            const bool db = !((j < 64) ? ((r0 >> j) & 1ull) : ((r1 >> (j - 64)) & 1ull));
            if (sb) {
                msum2 = fmaf(mv, (float)pref, msum2);   // cnt_j = #sames strictly before j
                ++pref;
                msum1 = fmaf(mv, (float)(S - pref), msum1); // cnt_k = #sames strictly after j
            }
            if (db) { ++dcnt; mdsum += mv; }
        }
        const float ds = (float)dcnt;
        t1s[i] = mdsum * P - msum1 * ds;
        t2s[i] = mdsum * P - msum2 * ds;
        qs[i]  = P * ds;
    }
    __syncthreads();
    if (tid == 0) {
        float sum1 = 0.f, sum2 = 0.f, Q = 0.f;
        for (int i = 0; i < NN; ++i) { sum1 += t1s[i]; sum2 += t2s[i]; Q += qs[i]; }
        const float md = (sum1 + sum2) / fmaxf(2.0f * Q, 1.0f);
        epsOut[0] = fmaxf(md * 0.5f, 0.0f);   // relu(mean_delta / K_DELTA), K_DELTA = 2
    }
}

__global__ __launch_bounds__(128) void k_cbits(
    const float* __restrict__ mat, const float* __restrict__ epsP,
    const uint64_t* __restrict__ samesW, const uint64_t* __restrict__ srawW,
    uint64_t* __restrict__ cbits)
{
    const int i = blockIdx.x;
    const int tid = threadIdx.x;
    __shared__ float row[NN];
    if (tid < NN) row[tid] = mat[i*NN + tid];
    __syncthreads();
    if (tid >= NN) return;
    const int p = tid;
    uint64_t c0 = 0, c1 = 0;
    const uint64_t s0 = samesW[i*2], s1 = samesW[i*2+1];
    const bool sp = (p < 64) ? ((s0 >> p) & 1ull) : ((s1 >> (p - 64)) & 1ull);
    if (sp) {
        const float eps = epsP[0];
        const float mp = row[p];
        const uint64_t d0 = ~srawW[i*2], d1 = ~srawW[i*2+1];
        for (int n = 0; n < NN; ++n) {
            const float m = row[n] - mp;
            const bool db = (n < 64) ? ((d0 >> n) & 1ull) : ((d1 >> (n - 64)) & 1ull);
            if (db && (m > 0.0f) && (m <= eps)) {
                if (n < 64) c0 |= 1ull << n; else c1 |= 1ull << (n - 64);
            }
        }
    }
    cbits[(i*NN + p)*2]     = c0;
    cbits[(i*NN + p)*2 + 1] = c1;
}

// grid (9, 9216): blockIdx.y = i*96+j ; 2304 float4 per (i,j) covering (k, n).
// Exact R0 structure — the proven-fastest variant (82,944 tiny blocks, one
// 16-B store per thread). Two restructure attempts (block-per-rem, 9 stores
// per thread, with and without nontemporal) both measured ~+10 us slower.
__global__ __launch_bounds__(256) void k_mask(
    const uint64_t* __restrict__ cbits, float4* __restrict__ out)
{
    const uint32_t rem = blockIdx.y;                       // i*96 + j
    const uint32_t pos = blockIdx.x * 256u + threadIdx.x;  // 0..2303 = k*24 + q
    const uint32_t k = pos / 24u;
    const uint32_t q = pos - k * 24u;
    const uint32_t i = rem / 96u;
    const uint32_t j = rem - i * 96u;
    float4 v = {0.f, 0.f, 0.f, 0.f};
    if (j < k) {
        const uint32_t b = i * 96u + k;
        const uint64_t w0 = cbits[rem*2]   & cbits[b*2];
        const uint64_t w1 = cbits[rem*2+1] & cbits[b*2+1];
        const uint32_t n0 = q * 4u;
        const uint64_t w = (n0 < 64u) ? w0 : w1;
        const uint32_t sh = n0 & 63u;
        v.x = (float)((w >> sh) & 1ull);
        v.y = (float)((w >> (sh + 1)) & 1ull);
        v.z = (float)((w >> (sh + 2)) & 1ull);
        v.w = (float)((w >> (sh + 3)) & 1ull);
    }
    out[(size_t)rem * 2304u + pos] = v;
}

extern "C" void kernel_launch(void* const* d_in, const int* in_sizes, int n_in,
                              void* d_out, int out_size, void* d_ws, size_t ws_size,
                              hipStream_t stream) {
    const float* logits = (const float*)d_in[0];
    const float* labels = (const float*)d_in[1];
    char* ws = (char*)d_ws;
    float*    mat    = (float*)(ws + 0);
    float*    eps    = (float*)(ws + 36864);
    uint64_t* samesW = (uint64_t*)(ws + 36928);
    uint64_t* srawW  = (uint64_t*)(ws + 38464);
    uint64_t* cbits  = (uint64_t*)(ws + 40000);

    hipLaunchKernelGGL(k_prep, dim3(1), dim3(512), 0, stream,
                       logits, labels, mat, eps, samesW, srawW);
    hipLaunchKernelGGL(k_cbits, dim3(NN), dim3(128), 0, stream,
                       mat, eps, samesW, srawW, cbits);
    hipLaunchKernelGGL(k_mask, dim3(9, NN*NN), dim3(256), 0, stream,
                       cbits, (float4*)d_out);
}